// Round 2
// baseline (137.661 us; speedup 1.0000x reference)
//
#include <hip/hip_runtime.h>
#include <hip/hip_bf16.h>
#include <math.h>

typedef __hip_bfloat16 bf16;
typedef __attribute__((ext_vector_type(8))) short short8;
typedef __attribute__((ext_vector_type(4))) short sh4;
typedef __attribute__((ext_vector_type(4))) float f32x4;

static __device__ __forceinline__ float bf2f(bf16 h) { return __bfloat162float(h); }
static __device__ __forceinline__ short f2bfs(float f) {
    bf16 h = __float2bfloat16(f);
    return *reinterpret_cast<short*>(&h);
}
static __device__ __forceinline__ short8 cvt8(float4 a, float4 b) {
    short8 o;
    o[0] = f2bfs(a.x); o[1] = f2bfs(a.y); o[2] = f2bfs(a.z); o[3] = f2bfs(a.w);
    o[4] = f2bfs(b.x); o[5] = f2bfs(b.y); o[6] = f2bfs(b.z); o[7] = f2bfs(b.w);
    return o;
}

constexpr int Bn = 8;
constexpr int C  = 256;
constexpr int N  = 1024;     // H*W
constexpr int NH = 8;
constexpr int HD = 32;
constexpr int TS = 264;      // LDS tile stride (shorts)
constexpr float SCALE = 0.17677669529663687f;  // 1/sqrt(32)
// log2(e) folded into the q scale so K2's softmax can use raw v_exp_f32 (2^x)
constexpr float SCALE_E = 0.17677669529663687f * 1.4426950408889634f;

// ---------------------------------------------------------------------------
// K0: convert Wq|Wk|Wv|Wp f32 -> Wb bf16 [4][256][256]. 16 blocks.
// ---------------------------------------------------------------------------
__global__ __launch_bounds__(256) void k_prep(
    const float* __restrict__ Wq, const float* __restrict__ Wk,
    const float* __restrict__ Wv, const float* __restrict__ Wp,
    bf16* __restrict__ Wb)
{
    const int tid = threadIdx.x;
    const int mat = blockIdx.x >> 2, seg = blockIdx.x & 3;
    const float* src = (mat == 0) ? Wq : (mat == 1) ? Wk : (mat == 2) ? Wv : Wp;
    short* dst = reinterpret_cast<short*>(Wb) + (size_t)mat * 256 * 256;
#pragma unroll
    for (int i = 0; i < 16; ++i) {
        int f4 = seg * 4096 + i * 256 + tid;
        float4 v = reinterpret_cast<const float4*>(src)[f4];
        sh4 o;
        o[0] = f2bfs(v.x); o[1] = f2bfs(v.y); o[2] = f2bfs(v.z); o[3] = f2bfs(v.w);
        *reinterpret_cast<sh4*>(dst + (size_t)f4 * 4) = o;
    }
}

// ---------------------------------------------------------------------------
// K1: fused transpose + gates + q/k/v GEMM (R17/R18/R19-verified; only change
// this round: SCALE_E folds log2e into qo so K2 can use exp2f).
// 512 blocks = (b, 64-px tile, m-quarter), 3 A-loads : 12 MFMAs per k-step.
// ---------------------------------------------------------------------------
__global__ __launch_bounds__(256) void k_fused5(
    const float* __restrict__ x, const float* __restrict__ gq, const float* __restrict__ gk,
    const float* __restrict__ Wsq, const float* __restrict__ bsq,
    const float* __restrict__ Wsk, const float* __restrict__ bsk,
    const bf16* __restrict__ Wb,
    const float* __restrict__ bq, const float* __restrict__ bk, const float* __restrict__ bv,
    bf16* __restrict__ qo, bf16* __restrict__ ko, bf16* __restrict__ vo,
    float* __restrict__ sqg)
{
    __shared__ short T[64 * TS];     // [pixel][c], 33.8 KB
    __shared__ float sq_lds[64];
    __shared__ float sk_lds[64];

    const int tid  = threadIdx.x;
    const int wave = tid >> 6;
    const int lane = tid & 63;
    const int col  = lane & 15;
    const int quad = lane >> 4;

    const int b    = blockIdx.x >> 6;
    const int rest = blockIdx.x & 63;
    const int n0   = (rest >> 2) * 64;   // 16 tiles of 64 px
    const int mq   = rest & 3;           // m-quarter (192 rows)

    // ---- stage x^T tile: 256 c-rows x 64 pixels ----
    {
        const float* xp = x + (size_t)b * C * N + n0;
        const int row = tid >> 4;        // 0..15 (c within pass)
        const int f   = tid & 15;        // float4 within 64 pixels
#pragma unroll
        for (int p = 0; p < 16; ++p) {
            int c = p * 16 + row;
            float4 v = *reinterpret_cast<const float4*>(xp + (size_t)c * N + f * 4);
            T[(f * 4 + 0) * TS + c] = f2bfs(v.x);
            T[(f * 4 + 1) * TS + c] = f2bfs(v.y);
            T[(f * 4 + 2) * TS + c] = f2bfs(v.z);
            T[(f * 4 + 3) * TS + c] = f2bfs(v.w);
        }
    }
    __syncthreads();

    // ---- gates (wave 0 only): logits via MFMA over 4 B-frags ----
    if (wave == 0) {
        const float* wsrc = (col < 4) ? (Wsq + col * C) : (Wsk + (col & 3) * C);
        f32x4 ga[4] = {};
#pragma unroll
        for (int k0 = 0; k0 < 256; k0 += 32) {
            float4 w0 = *reinterpret_cast<const float4*>(wsrc + k0 + quad * 8);
            float4 w1 = *reinterpret_cast<const float4*>(wsrc + k0 + quad * 8 + 4);
            short8 af = cvt8(w0, w1);
#pragma unroll
            for (int cf = 0; cf < 4; ++cf) {
                short8 bfr = *reinterpret_cast<const short8*>(&T[(cf * 16 + col) * TS + k0 + quad * 8]);
                ga[cf] = __builtin_amdgcn_mfma_f32_16x16x32_bf16(af, bfr, ga[cf], 0, 0, 0);
            }
        }
        if (quad < 2) {
            const float* bsrc = (quad == 0) ? bsq : bsk;
            const float* gsrc = (quad == 0) ? gq : gk;
#pragma unroll
            for (int cf = 0; cf < 4; ++cf) {
                int n = n0 + cf * 16 + col;
                float a[4];
#pragma unroll
                for (int r = 0; r < 4; ++r)
                    a[r] = ga[cf][r] + bsrc[r] + gsrc[(size_t)b * 4 * N + (size_t)r * N + n];
                float mx = fmaxf(fmaxf(a[0], a[1]), fmaxf(a[2], a[3]));
                float e = 0.f;
#pragma unroll
                for (int r = 0; r < 4; ++r) e += __expf(a[r] - mx);
                float p0 = __expf(a[0] - mx) / e;
                if (quad == 0) {
                    sq_lds[cf * 16 + col] = p0;
                    if (mq == 0) sqg[b * N + n] = p0;
                } else {
                    sk_lds[cf * 16 + col] = p0;
                }
            }
        }
    }
    __syncthreads();

    // ---- GEMM: this block's 192-row M quarter; 3 A-frags x 4 B-frags ----
    const short* Ws = reinterpret_cast<const short*>(Wb);
    const int mbase = mq * 192 + wave * 48;
    f32x4 acc[3][4] = {};
#pragma unroll
    for (int k0 = 0; k0 < 256; k0 += 32) {
        short8 bfr[4];
#pragma unroll
        for (int cf = 0; cf < 4; ++cf)
            bfr[cf] = *reinterpret_cast<const short8*>(&T[(cf * 16 + col) * TS + k0 + quad * 8]);
#pragma unroll
        for (int i = 0; i < 3; ++i) {
            int m = mbase + i * 16;
            const short* wr = Ws + (size_t)(m >> 8) * 65536
                              + (size_t)((m & 255) + col) * 256 + k0 + quad * 8;
            short8 af = *reinterpret_cast<const short8*>(wr);
#pragma unroll
            for (int cf = 0; cf < 4; ++cf)
                acc[i][cf] = __builtin_amdgcn_mfma_f32_16x16x32_bf16(af, bfr[cf], acc[i][cf], 0, 0, 0);
        }
    }
    // epilogue (per-frag mat handles quarters spanning matrix boundaries)
#pragma unroll
    for (int i = 0; i < 3; ++i) {
        int m = mbase + i * 16;
        int mat = m >> 8;
        int cr  = (m & 255) + quad * 4;
        const float* bb = (mat == 0) ? bq : (mat == 1) ? bk : bv;
        float bias[4];
#pragma unroll
        for (int r = 0; r < 4; ++r) bias[r] = bb[cr + r];
        if (mat < 2) {
            short* op = reinterpret_cast<short*>((mat == 0) ? qo : ko) + (size_t)b * N * C;
#pragma unroll
            for (int cf = 0; cf < 4; ++cf) {
                int n = n0 + cf * 16 + col;
                float g = (mat == 0) ? sq_lds[cf * 16 + col] * SCALE_E
                                     : sk_lds[cf * 16 + col];
                sh4 pack;
#pragma unroll
                for (int r = 0; r < 4; ++r) pack[r] = f2bfs((acc[i][cf][r] + bias[r]) * g);
                *reinterpret_cast<sh4*>(op + (size_t)n * C + cr) = pack;
            }
        } else {
            bf16* op = vo + (size_t)b * C * N;
#pragma unroll
            for (int cf = 0; cf < 4; ++cf) {
                int n = n0 + cf * 16 + col;
#pragma unroll
                for (int r = 0; r < 4; ++r)
                    op[(size_t)(cr + r) * N + n] = __float2bfloat16(acc[i][cf][r] + bias[r]);
            }
        }
    }
}

// ---------------------------------------------------------------------------
// K2: attention + gated mix, double-buffered K/V LDS staging.
// THIS ROUND: q-tile halved 128->64 (wave owns 16 q rows), grid 512->1024
// blocks = 4 blocks/CU = 16 waves/CU (occupancy 2x; LDS 28.7 KB/block).
// XCD swizzle: all 16 q-tiles of one (b,h) land on the same XCD so the
// 128 KB K/V panel is XCD-L2-resident. Softmax uses exp2f (log2e folded
// into qo by K1).
// ---------------------------------------------------------------------------
__global__ __launch_bounds__(256) void k_attn6(
    const bf16* __restrict__ qo, const bf16* __restrict__ ko,
    const bf16* __restrict__ vo, const float* __restrict__ sqg,
    bf16* __restrict__ gt)
{
    __shared__ short P_lds[4][16 * 72];   //  9.2 KB
    __shared__ short K_lds[2][64 * 40];   // 10.2 KB
    __shared__ short V_lds[2][32 * 72];   //  9.2 KB  (total 28.7 KB)

    const int tid  = threadIdx.x;
    const int wave = tid >> 6;
    const int lane = tid & 63;
    const int col  = lane & 15;
    const int quad = lane >> 4;

    // XCD-aware decode: dispatch round-robins blockIdx over 8 XCDs; map so
    // each XCD owns 8 whole (b,h) chunks (16 consecutive tiles each).
    const int bi    = blockIdx.x;
    const int chunk = (bi & 7) * 8 + (bi >> 7);   // 0..63 == (b,h)
    const int tile  = (bi >> 3) & 15;
    const int b = chunk >> 3;
    const int h = chunk & 7;
    const int qbase = tile * 64 + wave * 16;

    const int skey = tid >> 2;          // 0..63
    const int sd   = (tid & 3) * 8;     // 0,8,16,24
    const int svd  = tid >> 3;          // 0..31
    const int svk  = (tid & 7) * 8;     // 0..56

    const short* kgp = reinterpret_cast<const short*>(ko) + (size_t)b * N * C + h * HD;
    const short* vgp = reinterpret_cast<const short*>(vo) + (size_t)b * C * N + (size_t)h * HD * N;
    const short* vp  = vgp;

    short8 qf;
    {
        const short* qp = reinterpret_cast<const short*>(qo) + (size_t)b * N * C + h * HD + quad * 8;
        qf = *reinterpret_cast<const short8*>(qp + (size_t)(qbase + col) * C);
    }

    float l = 0.f;
    f32x4 oac[2] = {};   // [dh]
    short* P = P_lds[wave];

    short8 kstage = *reinterpret_cast<const short8*>(kgp + (size_t)skey * C + sd);
    short8 vstage = *reinterpret_cast<const short8*>(vgp + (size_t)svd * N + svk);
    *reinterpret_cast<short8*>(&K_lds[0][skey * 40 + sd]) = kstage;
    *reinterpret_cast<short8*>(&V_lds[0][svd * 72 + svk]) = vstage;
    __syncthreads();

    for (int t = 0; t < 16; ++t) {
        const int tn = (t + 1) & 15;
        kstage = *reinterpret_cast<const short8*>(kgp + (size_t)(tn * 64 + skey) * C + sd);
        vstage = *reinterpret_cast<const short8*>(vgp + (size_t)svd * N + tn * 64 + svk);

        const short* Kb = K_lds[t & 1];
        const short* Vb = V_lds[t & 1];

        short8 kf[4];
#pragma unroll
        for (int c = 0; c < 4; ++c)
            kf[c] = *reinterpret_cast<const short8*>(&Kb[(c * 16 + col) * 40 + quad * 8]);

        {
            float s[16];
#pragma unroll
            for (int c = 0; c < 4; ++c) {
                f32x4 acc = {};
                acc = __builtin_amdgcn_mfma_f32_16x16x32_bf16(kf[c], qf, acc, 0, 0, 0);
#pragma unroll
                for (int r = 0; r < 4; ++r) s[c * 4 + r] = acc[r];
            }
            float p[16], lloc = 0.f;
#pragma unroll
            for (int i = 0; i < 16; ++i) { p[i] = exp2f(s[i]); lloc += p[i]; }
            lloc += __shfl_xor(lloc, 16, 64);
            lloc += __shfl_xor(lloc, 32, 64);
            l += lloc;
#pragma unroll
            for (int c = 0; c < 4; ++c) {
                sh4 pk;
#pragma unroll
                for (int r = 0; r < 4; ++r) pk[r] = f2bfs(p[c * 4 + r]);
                *reinterpret_cast<sh4*>(&P[col * 72 + c * 16 + quad * 4]) = pk;
            }
        }

#pragma unroll
        for (int kg = 0; kg < 2; ++kg) {
            short8 vf[2];
#pragma unroll
            for (int dh = 0; dh < 2; ++dh)
                vf[dh] = *reinterpret_cast<const short8*>(&Vb[(dh * 16 + col) * 72 + kg * 32 + quad * 8]);
            short8 pf = *reinterpret_cast<const short8*>(&P[col * 72 + kg * 32 + quad * 8]);
#pragma unroll
            for (int dh = 0; dh < 2; ++dh)
                oac[dh] = __builtin_amdgcn_mfma_f32_16x16x32_bf16(vf[dh], pf, oac[dh], 0, 0, 0);
        }

        *reinterpret_cast<short8*>(&K_lds[(t + 1) & 1][skey * 40 + sd]) = kstage;
        *reinterpret_cast<short8*>(&V_lds[(t + 1) & 1][svd * 72 + svk]) = vstage;
        __syncthreads();
    }

    // epilogue: gated mix, pixel-major packed stores
    {
        const int q = qbase + col;
        const float invl = 1.f / l;
        const float sqv  = sqg[b * N + q];
        const float hv   = 1.f - sqv;
        short* gp = reinterpret_cast<short*>(gt) + ((size_t)b * N + q) * C + h * HD + quad * 4;
#pragma unroll
        for (int dh = 0; dh < 2; ++dh) {
            sh4 pack;
#pragma unroll
            for (int r = 0; r < 4; ++r) {
                int d = dh * 16 + quad * 4 + r;
                float vb = bf2f(*reinterpret_cast<const bf16*>(vp + (size_t)d * N + q));
                pack[r] = f2bfs(sqv * (oac[dh][r] * invl) + hv * vb);
            }
            *reinterpret_cast<sh4*>(gp + dh * 16) = pack;
        }
    }
}

// ---------------------------------------------------------------------------
// K3: projection MFMA GEMM, 64m x 64n blocks with staged G tile.
// grid (4, 16, 8) = 512 blocks = 2/CU. Wave = 1 m-frag x 4 n-frags:
// per k-step 1 A-global : 4 B-LDS : 4 MFMAs (0.25 loads/MFMA).
// ---------------------------------------------------------------------------
__global__ __launch_bounds__(256) void k_projm5(
    const bf16* __restrict__ gt, const bf16* __restrict__ Wpb,
    const float* __restrict__ bp, float* __restrict__ out)
{
    __shared__ short G[64 * TS];   // [pixel][c], 33.8 KB

    const int tid  = threadIdx.x;
    const int wave = tid >> 6, lane = tid & 63;
    const int col  = lane & 15, quad = lane >> 4;
    const int mrow = blockIdx.x * 64 + wave * 16;    // wave owns 16 m rows
    const int b    = blockIdx.z;
    const int n0   = blockIdx.y * 64;

    // ---- stage gt tile: 64 pixels x 256 c (no transpose, no convert) ----
    {
        const short* gp = reinterpret_cast<const short*>(gt) + ((size_t)b * N + n0) * C;
        const int px = tid >> 2;          // 0..63
        const int c0 = (tid & 3) * 64;    // 0,64,128,192
#pragma unroll
        for (int j = 0; j < 8; ++j) {
            short8 v = *reinterpret_cast<const short8*>(gp + (size_t)px * C + c0 + j * 8);
            *reinterpret_cast<short8*>(&G[px * TS + c0 + j * 8]) = v;
        }
    }
    __syncthreads();

    const short* Wm = reinterpret_cast<const short*>(Wpb);

    f32x4 acc[4] = {};   // [nfrag]
#pragma unroll
    for (int k0 = 0; k0 < 256; k0 += 32) {
        short8 af = *reinterpret_cast<const short8*>(Wm + (size_t)(mrow + col) * 256 + k0 + quad * 8);
#pragma unroll
        for (int cf = 0; cf < 4; ++cf) {
            short8 bfr = *reinterpret_cast<const short8*>(&G[(cf * 16 + col) * TS + k0 + quad * 8]);
            acc[cf] = __builtin_amdgcn_mfma_f32_16x16x32_bf16(af, bfr, acc[cf], 0, 0, 0);
        }
    }

    const int cr = mrow + quad * 4;
    float bias[4];
#pragma unroll
    for (int r = 0; r < 4; ++r) bias[r] = bp[cr + r];
    float* op = out + (size_t)b * C * N;
#pragma unroll
    for (int cf = 0; cf < 4; ++cf) {
        int n = n0 + cf * 16 + col;
#pragma unroll
        for (int r = 0; r < 4; ++r)
            op[(size_t)(cr + r) * N + n] = acc[cf][r] + bias[r];
    }
}

// ---------------------------------------------------------------------------
// Workspace (bytes):
//   [0, 32K)        sqg f32 [8][1024]
//   [32K, 544K)     Wb bf16 [4][256][256]  (q,k,v,p)
//   [544K, +4M)     qo bf16 [8][1024][256] (pixel-major, sq*SCALE*log2e folded)
//   +4M             ko bf16 [8][1024][256] (pixel-major, sk folded)
//   +4M             vo bf16 [8][256][1024] (d-major)
//   +4M             gt bf16 [8][1024][256] (gated rows, pixel-major)
// ---------------------------------------------------------------------------
extern "C" void kernel_launch(void* const* d_in, const int* in_sizes, int n_in,
                              void* d_out, int out_size, void* d_ws, size_t ws_size,
                              hipStream_t stream)
{
    const float* x   = (const float*)d_in[0];
    const float* gq  = (const float*)d_in[1];
    const float* gk  = (const float*)d_in[2];
    const float* Wsq = (const float*)d_in[3];
    const float* bsq = (const float*)d_in[4];
    const float* Wsk = (const float*)d_in[5];
    const float* bsk = (const float*)d_in[6];
    const float* Wq  = (const float*)d_in[7];
    const float* bq  = (const float*)d_in[8];
    const float* Wk  = (const float*)d_in[9];
    const float* bk  = (const float*)d_in[10];
    const float* Wv  = (const float*)d_in[11];
    const float* bv  = (const float*)d_in[12];
    const float* Wp  = (const float*)d_in[13];
    const float* bp  = (const float*)d_in[14];

    char* ws = (char*)d_ws;
    float* sqg = (float*)ws;
    bf16* Wb   = (bf16*)(ws + 32768);
    bf16* qo   = (bf16*)(ws + 32768 + 524288);
    bf16* ko   = qo + (size_t)Bn * N * C;
    bf16* vo   = ko + (size_t)Bn * N * C;
    bf16* gt   = vo + (size_t)Bn * C * N;
    float* out = (float*)d_out;

    k_prep<<<16, 256, 0, stream>>>(Wq, Wk, Wv, Wp, Wb);
    k_fused5<<<512, 256, 0, stream>>>(x, gq, gk, Wsq, bsq, Wsk, bsk,
                                      Wb, bq, bk, bv, qo, ko, vo, sqg);
    k_attn6<<<1024, 256, 0, stream>>>(qo, ko, vo, sqg, gt);
    k_projm5<<<dim3(4, 16, 8), 256, 0, stream>>>(gt, Wb + 3 * 65536, bp, out);
}